// Round 12
// baseline (502.595 us; speedup 1.0000x reference)
//
#include <hip/hip_runtime.h>
#include <hip/hip_bf16.h>

#define DIN 96
#define DOUT 32
#define NH 4
#define DTOT 128          // NH * DOUT, concat output width
#define SLOPE 0.2f
#define NPBF 64           // nodes per block in feat_kernel (4 per thread)
#define KCH 24            // k-chunk size (4 chunks, double-buffered LDS)
#define BSH 7             // bucket shift: 128 src nodes per parent bucket
#define BNODES 128
#define MAXB 1024         // max parent buckets (N <= 131072)
#define EPB 4096          // edges per scatter block
#define BCAP 5632         // fixed parent-bucket capacity (E/nb=4096 avg +24 sigma)
#define QSL  2304         // quarter wbuf capacity (avg 1024, +39 sigma)
#define SLSZ 2432         // quarter slist capacity (QSL + 32*4 pad slack)
#define GSTR 16           // gcur counter stride in ints (64B cacheline)

// pack two fp32 -> two bf16 (RNE) in one uint
__device__ __forceinline__ unsigned int packbf2(float lo, float hi) {
    unsigned int a = __float_as_uint(lo), b = __float_as_uint(hi);
    a += 0x7fffu + ((a >> 16) & 1u);
    b += 0x7fffu + ((b >> 16) & 1u);
    return (a >> 16) | (b & 0xffff0000u);
}

// ---------------------------------------------------------------------------
// feat_kernel v5: h[n] = x[n] @ W (all heads) -> packed bf16, plus per-node
// attention exp factors.
// KEY CHANGE (R12): W staged in 4 k-chunks of 24, double-buffered LDS
// (25.6 KB total vs 49.25 KB) -> 6 blocks/CU = 24 waves/CU (was 12).
// R4/R11 evidence: feat is ~80% stalled (VALUBusy 19.8%, HBM 357 GB/s
// latency-bound) at 2-3 waves/SIMD; doubling resident waves attacks the
// load->use stall regardless of which memory path it is. Chunk c+1 stages
// while chunk c computes (one barrier per chunk). FMA order unchanged
// (k ascending) -> bit-identical numerics.
// Block 0 also zeroes the gcur cursors (replaces the memset dispatch).
// ---------------------------------------------------------------------------
__global__ __launch_bounds__(256) void feat_kernel(
    const float* __restrict__ x, const float* __restrict__ W,
    const float* __restrict__ a,
    unsigned int* __restrict__ hq,      // [N*64] packed bf16 pairs
    float2* __restrict__ usrc, float2* __restrict__ vdst,
    int* __restrict__ gcur0, int n_nodes, int nb)
{
    __shared__ float Wlo[2][KCH * 64];  // [buf][kl*64 + cbi*4 + jj], cols 8cbi+jj
    __shared__ float Whi[2][KCH * 64];  // [buf][kl*64 + cbi*4 + jj], cols 8cbi+4+jj
    __shared__ float al[NH * 2 * DOUT];
    const int t = threadIdx.x;

    if (blockIdx.x == 0)
        for (int i = t; i < nb; i += 256) gcur0[i * GSTR] = 0;

    for (int i = t; i < NH * 2 * DOUT; i += 256) al[i] = a[i];

    // stage chunk 0 into buffer 0
    for (int i = t; i < KCH * DTOT; i += 256) {
        int kl = i >> 7, c = i & 127;       // c = output col 0..127
        int head = c >> 5, j = c & 31;
        float w = W[head * (DIN * DOUT) + kl * DOUT + j];
        int cbi = c >> 3, jj = c & 7;
        if (jj < 4) Wlo[0][(kl << 6) + (cbi << 2) + jj] = w;
        else        Whi[0][(kl << 6) + (cbi << 2) + (jj - 4)] = w;
    }
    __syncthreads();

    const int cbi = t & 15;             // column block: cols 8*cbi .. 8*cbi+7
    const int ng = t >> 4;              // node group (4 nodes)
    const int node0 = blockIdx.x * NPBF;
    const int g0 = node0 + ng * 4;

    bool ok[4];
    const float* xp[4];
#pragma unroll
    for (int i = 0; i < 4; ++i) {
        ok[i] = (g0 + i) < n_nodes;
        xp[i] = x + (size_t)(g0 + i) * DIN;
    }

    float acc[4][8];
#pragma unroll
    for (int i = 0; i < 4; ++i)
#pragma unroll
        for (int j = 0; j < 8; ++j) acc[i][j] = 0.f;

    for (int ch = 0; ch < DIN / KCH; ++ch) {
        const int cur = ch & 1;
        const int nxt = cur ^ 1;
        // stage next chunk into the other buffer (overlaps compute below)
        if (ch + 1 < DIN / KCH) {
            const int kb = (ch + 1) * KCH;
            for (int i = t; i < KCH * DTOT; i += 256) {
                int kl = i >> 7, c = i & 127;
                int head = c >> 5, j = c & 31;
                float w = W[head * (DIN * DOUT) + (kb + kl) * DOUT + j];
                int cb2 = c >> 3, jj = c & 7;
                if (jj < 4) Wlo[nxt][(kl << 6) + (cb2 << 2) + jj] = w;
                else        Whi[nxt][(kl << 6) + (cb2 << 2) + (jj - 4)] = w;
            }
        }
        // compute current chunk (k ascending, same FMA order as before)
        const int kb0 = ch * KCH;
        for (int kl = 0; kl < KCH; kl += 4) {
            float4 xv[4];
#pragma unroll
            for (int i = 0; i < 4; ++i)
                xv[i] = ok[i] ? *(const float4*)(xp[i] + kb0 + kl)
                              : make_float4(0.f, 0.f, 0.f, 0.f);
#pragma unroll
            for (int kk = 0; kk < 4; ++kk) {
                const float4 wlo = *(const float4*)&Wlo[cur][((kl + kk) << 6) + (cbi << 2)];
                const float4 whi = *(const float4*)&Whi[cur][((kl + kk) << 6) + (cbi << 2)];
#pragma unroll
                for (int i = 0; i < 4; ++i) {
                    const float xvv = (kk == 0) ? xv[i].x : (kk == 1) ? xv[i].y
                                     : (kk == 2) ? xv[i].z : xv[i].w;
                    acc[i][0] = fmaf(xvv, wlo.x, acc[i][0]);
                    acc[i][1] = fmaf(xvv, wlo.y, acc[i][1]);
                    acc[i][2] = fmaf(xvv, wlo.z, acc[i][2]);
                    acc[i][3] = fmaf(xvv, wlo.w, acc[i][3]);
                    acc[i][4] = fmaf(xvv, whi.x, acc[i][4]);
                    acc[i][5] = fmaf(xvv, whi.y, acc[i][5]);
                    acc[i][6] = fmaf(xvv, whi.z, acc[i][6]);
                    acc[i][7] = fmaf(xvv, whi.w, acc[i][7]);
                }
            }
        }
        // one barrier per chunk: staging of nxt complete (for next compute)
        // AND compute of cur complete (before nxt+1 overwrites it)
        __syncthreads();
    }

    const int head = cbi >> 2;
    const int j0 = (cbi & 3) << 3;
#pragma unroll
    for (int i = 0; i < 4; ++i) {
        float ps = 0.f, pd = 0.f;
#pragma unroll
        for (int j = 0; j < 8; ++j) {
            ps += acc[i][j] * al[head * 64 + j0 + j];
            pd += acc[i][j] * al[head * 64 + 32 + j0 + j];
        }
        ps += __shfl_xor(ps, 1); ps += __shfl_xor(ps, 2);
        pd += __shfl_xor(pd, 1); pd += __shfl_xor(pd, 2);
        const int g = g0 + i;
        if (ok[i]) {
            uint4 pk;
            pk.x = packbf2(acc[i][0], acc[i][1]);
            pk.y = packbf2(acc[i][2], acc[i][3]);
            pk.z = packbf2(acc[i][4], acc[i][5]);
            pk.w = packbf2(acc[i][6], acc[i][7]);
            *(uint4*)&hq[(size_t)g * 64 + (cbi << 2)] = pk;
            if ((cbi & 3) == 0) {
                usrc[g * NH + head] = make_float2(__expf(-ps), __expf(-SLOPE * ps));
                vdst[g * NH + head] = make_float2(__expf(-pd), __expf(-SLOPE * pd));
            }
        }
    }
}

// ---------------------------------------------------------------------------
// binscatter (R8 form, measured 61us @ R11): scatter edges (packed srcl|dst)
// into fixed-capacity parent-bucket regions. 16 edges/thread reg-staged,
// LDS hist, run reservation on cacheline-padded gcur (zeroed by feat blk 0).
// Final gcur[b*GSTR] == bucket count.
// ---------------------------------------------------------------------------
__global__ __launch_bounds__(256) void binscatter_kernel(
    const int* __restrict__ esrc, const int* __restrict__ edst,
    int* __restrict__ gcur, unsigned int* __restrict__ binned,
    int n_edges, int nb)
{
    __shared__ int bc[MAXB];
    const int t = threadIdx.x;
    for (int i = t; i < nb; i += 256) bc[i] = 0;
    __syncthreads();

    const int base = blockIdx.x * EPB;
    const int end = min(base + EPB, n_edges);
    const bool full = (end - base) == EPB;

    int se[16], de[16];
    if (full) {
        const int4* s4p = (const int4*)(esrc + base);
        const int4* d4p = (const int4*)(edst + base);
#pragma unroll
        for (int j = 0; j < 4; ++j) {
            int4 s4 = s4p[j * 256 + t];
            int4 d4 = d4p[j * 256 + t];
            se[j * 4 + 0] = s4.x; se[j * 4 + 1] = s4.y;
            se[j * 4 + 2] = s4.z; se[j * 4 + 3] = s4.w;
            de[j * 4 + 0] = d4.x; de[j * 4 + 1] = d4.y;
            de[j * 4 + 2] = d4.z; de[j * 4 + 3] = d4.w;
        }
#pragma unroll
        for (int j = 0; j < 16; ++j)
            atomicAdd(&bc[se[j] >> BSH], 1);
    } else {
#pragma unroll
        for (int j = 0; j < 16; ++j) {
            const int e = base + j * 256 + t;
            se[j] = (e < end) ? esrc[e] : 0;
            de[j] = (e < end) ? edst[e] : 0;
            if (e < end) atomicAdd(&bc[se[j] >> BSH], 1);
        }
    }
    __syncthreads();

    for (int i = t; i < nb; i += 256) {
        int c = bc[i];
        bc[i] = (c > 0) ? (i * BCAP + atomicAdd(&gcur[i * GSTR], c)) : 0;
    }
    __syncthreads();

    if (full) {
#pragma unroll
        for (int j = 0; j < 16; ++j) {
            int s = se[j];
            int pos = atomicAdd(&bc[s >> BSH], 1);
            binned[pos] = ((unsigned int)(s & (BNODES - 1)) << 17) | (unsigned int)de[j];
        }
    } else {
#pragma unroll
        for (int j = 0; j < 16; ++j) {
            const int e = base + j * 256 + t;
            if (e < end) {
                int s = se[j];
                int pos = atomicAdd(&bc[s >> BSH], 1);
                binned[pos] = ((unsigned int)(s & (BNODES - 1)) << 17) | (unsigned int)de[j];
            }
        }
    }
}

// ---------------------------------------------------------------------------
// bucket_kernel (R8 form, 164-166us = at the scattered-row ceiling):
// 4 quarter-blocks per parent bucket. Filtered pass over the parent's binned
// words -> compact LDS wbuf + hist; 32-entry scan; LDS fine-sort into slist;
// then the proven register-pipeline gather. ~19.3 KB LDS, 3128 blocks.
// ---------------------------------------------------------------------------
__global__ __launch_bounds__(512) void bucket_kernel(
    const int* __restrict__ gcur,
    const unsigned int* __restrict__ binned,
    const unsigned int* __restrict__ hv,    // [N*64] packed bf16 pairs
    const float2* __restrict__ usrc, const float2* __restrict__ vdst,
    float* __restrict__ out, int n_nodes)
{
    __shared__ unsigned int wbuf[QSL];
    __shared__ __align__(16) int slist[SLSZ];
    __shared__ int dcnt[32];
    __shared__ int sc[32];
    __shared__ int dcur[32];
    __shared__ int qn_s;
    const int t = threadIdx.x;
    const int p = (int)blockIdx.x >> 2;
    const int q = (int)blockIdx.x & 3;
    const unsigned pbase = (unsigned)p * BCAP;
    int cnt = gcur[p * GSTR];
    if (cnt > BCAP - 512) cnt = BCAP - 512;   // safety clamp (never triggers)
    const int node0 = (p << BSH) + (q << 5);

    if (t < 32) dcnt[t] = 0;
    if (t == 0) qn_s = 0;
    __syncthreads();

    // single filtered pass: compact quarter's words into wbuf + histogram
    for (int i = t; i < cnt; i += 512) {
        unsigned int w = binned[pbase + i];
        int s = (int)(w >> 17);
        if ((s >> 5) == q) {
            int pos = atomicAdd(&qn_s, 1);
            if (pos < QSL) {
                wbuf[pos] = w;
                atomicAdd(&dcnt[s & 31], 1);
            }
        }
    }
    __syncthreads();
    int qn = qn_s; if (qn > QSL) qn = QSL;

    int pd = 0;
    if (t < 32) { pd = (dcnt[t] + 3) & ~3; sc[t] = pd; }
    __syncthreads();
    for (int off = 1; off < 32; off <<= 1) {
        int v = 0;
        if (t < 32 && t >= off) v = sc[t - off];
        __syncthreads();
        if (t < 32) sc[t] += v;
        __syncthreads();
    }
    if (t < 32) dcur[t] = sc[t] - pd;     // local 4-aligned start
    __syncthreads();
    for (int i = t; i < qn; i += 512) {
        unsigned int w = wbuf[i];
        int pos = atomicAdd(&dcur[(w >> 17) & 31], 1);
        slist[pos] = (int)(w & 0x1ffffu);
    }
    __syncthreads();
    // dcur[n] is now start+deg, so start = dcur[n] - dcnt[n]

    // ------------------------- gather phase -------------------------
    const int l = t & 63;          // cols {2l, 2l+1}
    const int head = l >> 4;
    const unsigned loff = (unsigned)l << 2;     // byte offset in hv row (256B)
    const unsigned hoff = (unsigned)head << 3;  // byte offset in vdst row (32B)
    const char* __restrict__ hvb = (const char*)hv;
    const char* __restrict__ vdb = (const char*)vdst;
    const int sub = t >> 6;        // wave id 0..7 (uniform per wave)

#define LDV(c) (*(const float2*)(vdb + ((((unsigned)(c)) << 5) + hoff)))
#define LDW(c) (*(const unsigned int*)(hvb + ((((unsigned)(c)) << 8) + loff)))
#define COMP(vv, ww, AX, AY) do {                                   \
        float e_ = fminf(u.x * (vv).x, u.y * (vv).y);               \
        AX = fmaf(e_, __uint_as_float((ww) << 16), AX);             \
        AY = fmaf(e_, __uint_as_float((ww) & 0xffff0000u), AY);     \
    } while (0)

    for (int r = 0; r < 4; ++r) {
        const int nd = r * 8 + sub;
        const int node = node0 + nd;
        if (node >= n_nodes) break;           // wave-uniform exit
        const int d = dcnt[nd];
        const int beg = dcur[nd] - d;         // local, multiple of 4
        const float2 u = usrc[(unsigned)node * 4u + head];

        float ax0 = 0.f, ay0 = 0.f, ax1 = 0.f, ay1 = 0.f;
        float ax2 = 0.f, ay2 = 0.f, ax3 = 0.f, ay3 = 0.f;
        int k = 0;
        if (d >= 4) {
            int4 cA = *(const int4*)&slist[beg];
            float2 vA0 = LDV(cA.x), vA1 = LDV(cA.y), vA2 = LDV(cA.z), vA3 = LDV(cA.w);
            unsigned wA0 = LDW(cA.x), wA1 = LDW(cA.y), wA2 = LDW(cA.z), wA3 = LDW(cA.w);

            for (; k + 12 <= d; k += 8) {
                int4 cB = *(const int4*)&slist[beg + k + 4];
                float2 vB0 = LDV(cB.x), vB1 = LDV(cB.y), vB2 = LDV(cB.z), vB3 = LDV(cB.w);
                unsigned wB0 = LDW(cB.x), wB1 = LDW(cB.y), wB2 = LDW(cB.z), wB3 = LDW(cB.w);
                COMP(vA0, wA0, ax0, ay0); COMP(vA1, wA1, ax1, ay1);
                COMP(vA2, wA2, ax2, ay2); COMP(vA3, wA3, ax3, ay3);
                int4 cN = *(const int4*)&slist[beg + k + 8];
                vA0 = LDV(cN.x); vA1 = LDV(cN.y); vA2 = LDV(cN.z); vA3 = LDV(cN.w);
                wA0 = LDW(cN.x); wA1 = LDW(cN.y); wA2 = LDW(cN.z); wA3 = LDW(cN.w);
                COMP(vB0, wB0, ax0, ay0); COMP(vB1, wB1, ax1, ay1);
                COMP(vB2, wB2, ax2, ay2); COMP(vB3, wB3, ax3, ay3);
            }
            if (k + 8 <= d) {
                int4 cB = *(const int4*)&slist[beg + k + 4];
                float2 vB0 = LDV(cB.x), vB1 = LDV(cB.y), vB2 = LDV(cB.z), vB3 = LDV(cB.w);
                unsigned wB0 = LDW(cB.x), wB1 = LDW(cB.y), wB2 = LDW(cB.z), wB3 = LDW(cB.w);
                COMP(vA0, wA0, ax0, ay0); COMP(vA1, wA1, ax1, ay1);
                COMP(vA2, wA2, ax2, ay2); COMP(vA3, wA3, ax3, ay3);
                COMP(vB0, wB0, ax0, ay0); COMP(vB1, wB1, ax1, ay1);
                COMP(vB2, wB2, ax2, ay2); COMP(vB3, wB3, ax3, ay3);
                k += 8;
            } else {
                COMP(vA0, wA0, ax0, ay0); COMP(vA1, wA1, ax1, ay1);
                COMP(vA2, wA2, ax2, ay2); COMP(vA3, wA3, ax3, ay3);
                k += 4;
            }
        }
        for (; k < d; ++k) {
            int c = slist[beg + k];
            float2 v = LDV(c);
            unsigned w = LDW(c);
            COMP(v, w, ax0, ay0);
        }
        float rx = (ax0 + ax1) + (ax2 + ax3);
        float ry = (ay0 + ay1) + (ay2 + ay3);
        rx = rx > 0.f ? rx : __expf(rx) - 1.f;
        ry = ry > 0.f ? ry : __expf(ry) - 1.f;
        ((float2*)out)[(unsigned)node * 64u + l] = make_float2(rx, ry);
    }
#undef LDV
#undef LDW
#undef COMP
}

extern "C" void kernel_launch(void* const* d_in, const int* in_sizes, int n_in,
                              void* d_out, int out_size, void* d_ws, size_t ws_size,
                              hipStream_t stream)
{
    const float* x  = (const float*)d_in[0];
    const float* W  = (const float*)d_in[1];
    const float* a  = (const float*)d_in[2];
    const int* esrc = (const int*)d_in[3];
    const int* edst = (const int*)d_in[4];
    const int n_nodes = in_sizes[0] / DIN;
    const int n_edges = in_sizes[3];
    float* out = (float*)d_out;

    const int nb = (n_nodes + BNODES - 1) >> BSH;

    // workspace layout (~46.7 MB)
    unsigned int* hq = (unsigned int*)d_ws;                 // [N*64] bf16 pairs, 25.6MB
    float2* usrc = (float2*)(hq + (size_t)n_nodes * 64);    // [N*4]
    float2* vdst = usrc + (size_t)n_nodes * NH;             // [N*4]
    int* gcur   = (int*)(vdst + (size_t)n_nodes * NH);      // [MAXB*GSTR], 64KB
    unsigned int* binned = (unsigned int*)(gcur + MAXB * GSTR); // [nb*BCAP], 17.6MB

    feat_kernel<<<(n_nodes + NPBF - 1) / NPBF, 256, 0, stream>>>(
        x, W, a, hq, usrc, vdst, gcur, n_nodes, nb);

    binscatter_kernel<<<(n_edges + EPB - 1) / EPB, 256, 0, stream>>>(
        esrc, edst, gcur, binned, n_edges, nb);

    bucket_kernel<<<nb * 4, 512, 0, stream>>>(
        gcur, binned, hq, usrc, vdst, out, n_nodes);
}

// Round 13
// 404.680 us; speedup vs baseline: 1.2420x; 1.2420x over previous
//
#include <hip/hip_runtime.h>
#include <hip/hip_bf16.h>

#define DIN 96
#define DOUT 32
#define NH 4
#define DTOT 128          // NH * DOUT, concat output width
#define SLOPE 0.2f
#define NPBF 128          // nodes per feat block (col-split: 64 cols/block)
#define BSH 7             // bucket shift: 128 src nodes per parent bucket
#define BNODES 128
#define MAXB 1024         // max parent buckets (N <= 131072)
#define EPB 4096          // edges per scatter block
#define BCAP 5632         // fixed parent-bucket capacity (E/nb=4096 avg +24 sigma)
#define QSL  2304         // quarter wbuf capacity (avg 1024, +39 sigma)
#define SLSZ 2432         // quarter slist capacity (QSL + 32*4 pad slack)
#define GSTR 16           // gcur counter stride in ints (64B cacheline)

// pack two fp32 -> two bf16 (RNE) in one uint
__device__ __forceinline__ unsigned int packbf2(float lo, float hi) {
    unsigned int a = __float_as_uint(lo), b = __float_as_uint(hi);
    a += 0x7fffu + ((a >> 16) & 1u);
    b += 0x7fffu + ((b >> 16) & 1u);
    return (a >> 16) | (b & 0xffff0000u);
}

// ---------------------------------------------------------------------------
// feat_kernel v6 (column-split): each block computes 128 nodes x 64 cols
// (one head-pair). W half-tile = 24KB + al 1KB -> 25KB LDS -> 6 blocks/CU
// = 24 waves/CU (vs 12 in R8, ~4 in R12). R12's direct counters showed feat
// is x-load latency-bound (VALUBusy 20% = 256cy FMA / ~956cy load+FMA per
// k-step at ~1 wave/SIMD); doubling resident waves halves the exposed stall.
// Structure kept deliberately simple (monolithic stage, one barrier, no
// prefetch/chunking) -- R12's VGPR explosion (212) came from dbuf+chunking;
// this is the R4-proven 68-VGPR shape with a narrower tile.
// Numerics bit-identical: same k-ascending FMA chain per output column;
// each head's ps/pd reduction is entirely within one half.
// ---------------------------------------------------------------------------
__global__ __launch_bounds__(256) void feat_kernel(
    const float* __restrict__ x, const float* __restrict__ W,
    const float* __restrict__ a,
    unsigned int* __restrict__ hq,      // [N*64] packed bf16 pairs
    float2* __restrict__ usrc, float2* __restrict__ vdst,
    int n_nodes)
{
    __shared__ float Wlo[DIN * 32];     // [k][cbi*4 + jj], local cols 8*cbi + jj
    __shared__ float Whi[DIN * 32];     // [k][cbi*4 + jj], local cols 8*cbi+4+jj
    __shared__ float al[NH * 2 * DOUT];
    const int t = threadIdx.x;
    const int half = (int)blockIdx.x & 1;        // col half: heads 2h, 2h+1
    const int nodeblk = (int)blockIdx.x >> 1;

    // stage this half's W (heads 2*half, 2*half+1): 96 x 64 floats = 24KB
    for (int i = t; i < DIN * 64; i += 256) {
        int k = i >> 6, c = i & 63;              // c = local col 0..63
        int hl = c >> 5, j = c & 31;             // local head, col within head
        float w = W[(half * 2 + hl) * (DIN * DOUT) + k * DOUT + j];
        int cbi = c >> 3, jj = c & 7;            // cbi 0..7
        if (jj < 4) Wlo[(k << 5) + (cbi << 2) + jj] = w;
        else        Whi[(k << 5) + (cbi << 2) + (jj - 4)] = w;
    }
    for (int i = t; i < NH * 2 * DOUT; i += 256) al[i] = a[i];
    __syncthreads();

    const int cbi = t & 7;              // local col block: cols 8*cbi..8*cbi+7
    const int ng = t >> 3;              // node group (4 nodes), 0..31
    const int node0 = nodeblk * NPBF;
    const int g0 = node0 + ng * 4;

    bool ok[4];
    const float* xp[4];
#pragma unroll
    for (int i = 0; i < 4; ++i) {
        ok[i] = (g0 + i) < n_nodes;
        xp[i] = x + (size_t)(g0 + i) * DIN;
    }

    float acc[4][8];
#pragma unroll
    for (int i = 0; i < 4; ++i)
#pragma unroll
        for (int j = 0; j < 8; ++j) acc[i][j] = 0.f;

    for (int k = 0; k < DIN; k += 4) {
        float4 xv[4];
#pragma unroll
        for (int i = 0; i < 4; ++i)
            xv[i] = ok[i] ? *(const float4*)(xp[i] + k)
                          : make_float4(0.f, 0.f, 0.f, 0.f);
#pragma unroll
        for (int kk = 0; kk < 4; ++kk) {
            const float4 wlo = *(const float4*)&Wlo[((k + kk) << 5) + (cbi << 2)];
            const float4 whi = *(const float4*)&Whi[((k + kk) << 5) + (cbi << 2)];
#pragma unroll
            for (int i = 0; i < 4; ++i) {
                const float xvv = (kk == 0) ? xv[i].x : (kk == 1) ? xv[i].y
                                 : (kk == 2) ? xv[i].z : xv[i].w;
                acc[i][0] = fmaf(xvv, wlo.x, acc[i][0]);
                acc[i][1] = fmaf(xvv, wlo.y, acc[i][1]);
                acc[i][2] = fmaf(xvv, wlo.z, acc[i][2]);
                acc[i][3] = fmaf(xvv, wlo.w, acc[i][3]);
                acc[i][4] = fmaf(xvv, whi.x, acc[i][4]);
                acc[i][5] = fmaf(xvv, whi.y, acc[i][5]);
                acc[i][6] = fmaf(xvv, whi.z, acc[i][6]);
                acc[i][7] = fmaf(xvv, whi.w, acc[i][7]);
            }
        }
    }

    const int head = half * 2 + (cbi >> 2);
    const int j0 = (cbi & 3) << 3;
#pragma unroll
    for (int i = 0; i < 4; ++i) {
        float ps = 0.f, pd = 0.f;
#pragma unroll
        for (int j = 0; j < 8; ++j) {
            ps += acc[i][j] * al[head * 64 + j0 + j];
            pd += acc[i][j] * al[head * 64 + 32 + j0 + j];
        }
        ps += __shfl_xor(ps, 1); ps += __shfl_xor(ps, 2);
        pd += __shfl_xor(pd, 1); pd += __shfl_xor(pd, 2);
        const int g = g0 + i;
        if (ok[i]) {
            uint4 pk;
            pk.x = packbf2(acc[i][0], acc[i][1]);
            pk.y = packbf2(acc[i][2], acc[i][3]);
            pk.z = packbf2(acc[i][4], acc[i][5]);
            pk.w = packbf2(acc[i][6], acc[i][7]);
            // uint index of first col pair: (64*half + 8*cbi)/2
            *(uint4*)&hq[(size_t)g * 64 + half * 32 + (cbi << 2)] = pk;
            if ((cbi & 3) == 0) {
                usrc[g * NH + head] = make_float2(__expf(-ps), __expf(-SLOPE * ps));
                vdst[g * NH + head] = make_float2(__expf(-pd), __expf(-SLOPE * pd));
            }
        }
    }
}

// ---------------------------------------------------------------------------
// binscatter (R8 form, measured 61us @ R11): scatter edges (packed srcl|dst)
// into fixed-capacity parent-bucket regions. 16 edges/thread reg-staged,
// LDS hist, run reservation on cacheline-padded gcur (memset'd).
// Final gcur[b*GSTR] == bucket count.
// ---------------------------------------------------------------------------
__global__ __launch_bounds__(256) void binscatter_kernel(
    const int* __restrict__ esrc, const int* __restrict__ edst,
    int* __restrict__ gcur, unsigned int* __restrict__ binned,
    int n_edges, int nb)
{
    __shared__ int bc[MAXB];
    const int t = threadIdx.x;
    for (int i = t; i < nb; i += 256) bc[i] = 0;
    __syncthreads();

    const int base = blockIdx.x * EPB;
    const int end = min(base + EPB, n_edges);
    const bool full = (end - base) == EPB;

    int se[16], de[16];
    if (full) {
        const int4* s4p = (const int4*)(esrc + base);
        const int4* d4p = (const int4*)(edst + base);
#pragma unroll
        for (int j = 0; j < 4; ++j) {
            int4 s4 = s4p[j * 256 + t];
            int4 d4 = d4p[j * 256 + t];
            se[j * 4 + 0] = s4.x; se[j * 4 + 1] = s4.y;
            se[j * 4 + 2] = s4.z; se[j * 4 + 3] = s4.w;
            de[j * 4 + 0] = d4.x; de[j * 4 + 1] = d4.y;
            de[j * 4 + 2] = d4.z; de[j * 4 + 3] = d4.w;
        }
#pragma unroll
        for (int j = 0; j < 16; ++j)
            atomicAdd(&bc[se[j] >> BSH], 1);
    } else {
#pragma unroll
        for (int j = 0; j < 16; ++j) {
            const int e = base + j * 256 + t;
            se[j] = (e < end) ? esrc[e] : 0;
            de[j] = (e < end) ? edst[e] : 0;
            if (e < end) atomicAdd(&bc[se[j] >> BSH], 1);
        }
    }
    __syncthreads();

    for (int i = t; i < nb; i += 256) {
        int c = bc[i];
        bc[i] = (c > 0) ? (i * BCAP + atomicAdd(&gcur[i * GSTR], c)) : 0;
    }
    __syncthreads();

    if (full) {
#pragma unroll
        for (int j = 0; j < 16; ++j) {
            int s = se[j];
            int pos = atomicAdd(&bc[s >> BSH], 1);
            binned[pos] = ((unsigned int)(s & (BNODES - 1)) << 17) | (unsigned int)de[j];
        }
    } else {
#pragma unroll
        for (int j = 0; j < 16; ++j) {
            const int e = base + j * 256 + t;
            if (e < end) {
                int s = se[j];
                int pos = atomicAdd(&bc[s >> BSH], 1);
                binned[pos] = ((unsigned int)(s & (BNODES - 1)) << 17) | (unsigned int)de[j];
            }
        }
    }
}

// ---------------------------------------------------------------------------
// bucket_kernel (R8 form, 164-166us = at the scattered-row ceiling):
// 4 quarter-blocks per parent bucket. Filtered pass over the parent's binned
// words -> compact LDS wbuf + hist; 32-entry scan; LDS fine-sort into slist;
// then the proven register-pipeline gather. ~19.3 KB LDS, 3128 blocks.
// ---------------------------------------------------------------------------
__global__ __launch_bounds__(512) void bucket_kernel(
    const int* __restrict__ gcur,
    const unsigned int* __restrict__ binned,
    const unsigned int* __restrict__ hv,    // [N*64] packed bf16 pairs
    const float2* __restrict__ usrc, const float2* __restrict__ vdst,
    float* __restrict__ out, int n_nodes)
{
    __shared__ unsigned int wbuf[QSL];
    __shared__ __align__(16) int slist[SLSZ];
    __shared__ int dcnt[32];
    __shared__ int sc[32];
    __shared__ int dcur[32];
    __shared__ int qn_s;
    const int t = threadIdx.x;
    const int p = (int)blockIdx.x >> 2;
    const int q = (int)blockIdx.x & 3;
    const unsigned pbase = (unsigned)p * BCAP;
    int cnt = gcur[p * GSTR];
    if (cnt > BCAP - 512) cnt = BCAP - 512;   // safety clamp (never triggers)
    const int node0 = (p << BSH) + (q << 5);

    if (t < 32) dcnt[t] = 0;
    if (t == 0) qn_s = 0;
    __syncthreads();

    // single filtered pass: compact quarter's words into wbuf + histogram
    for (int i = t; i < cnt; i += 512) {
        unsigned int w = binned[pbase + i];
        int s = (int)(w >> 17);
        if ((s >> 5) == q) {
            int pos = atomicAdd(&qn_s, 1);
            if (pos < QSL) {
                wbuf[pos] = w;
                atomicAdd(&dcnt[s & 31], 1);
            }
        }
    }
    __syncthreads();
    int qn = qn_s; if (qn > QSL) qn = QSL;

    int pd = 0;
    if (t < 32) { pd = (dcnt[t] + 3) & ~3; sc[t] = pd; }
    __syncthreads();
    for (int off = 1; off < 32; off <<= 1) {
        int v = 0;
        if (t < 32 && t >= off) v = sc[t - off];
        __syncthreads();
        if (t < 32) sc[t] += v;
        __syncthreads();
    }
    if (t < 32) dcur[t] = sc[t] - pd;     // local 4-aligned start
    __syncthreads();
    for (int i = t; i < qn; i += 512) {
        unsigned int w = wbuf[i];
        int pos = atomicAdd(&dcur[(w >> 17) & 31], 1);
        slist[pos] = (int)(w & 0x1ffffu);
    }
    __syncthreads();
    // dcur[n] is now start+deg, so start = dcur[n] - dcnt[n]

    // ------------------------- gather phase -------------------------
    const int l = t & 63;          // cols {2l, 2l+1}
    const int head = l >> 4;
    const unsigned loff = (unsigned)l << 2;     // byte offset in hv row (256B)
    const unsigned hoff = (unsigned)head << 3;  // byte offset in vdst row (32B)
    const char* __restrict__ hvb = (const char*)hv;
    const char* __restrict__ vdb = (const char*)vdst;
    const int sub = t >> 6;        // wave id 0..7 (uniform per wave)

#define LDV(c) (*(const float2*)(vdb + ((((unsigned)(c)) << 5) + hoff)))
#define LDW(c) (*(const unsigned int*)(hvb + ((((unsigned)(c)) << 8) + loff)))
#define COMP(vv, ww, AX, AY) do {                                   \
        float e_ = fminf(u.x * (vv).x, u.y * (vv).y);               \
        AX = fmaf(e_, __uint_as_float((ww) << 16), AX);             \
        AY = fmaf(e_, __uint_as_float((ww) & 0xffff0000u), AY);     \
    } while (0)

    for (int r = 0; r < 4; ++r) {
        const int nd = r * 8 + sub;
        const int node = node0 + nd;
        if (node >= n_nodes) break;           // wave-uniform exit
        const int d = dcnt[nd];
        const int beg = dcur[nd] - d;         // local, multiple of 4
        const float2 u = usrc[(unsigned)node * 4u + head];

        float ax0 = 0.f, ay0 = 0.f, ax1 = 0.f, ay1 = 0.f;
        float ax2 = 0.f, ay2 = 0.f, ax3 = 0.f, ay3 = 0.f;
        int k = 0;
        if (d >= 4) {
            int4 cA = *(const int4*)&slist[beg];
            float2 vA0 = LDV(cA.x), vA1 = LDV(cA.y), vA2 = LDV(cA.z), vA3 = LDV(cA.w);
            unsigned wA0 = LDW(cA.x), wA1 = LDW(cA.y), wA2 = LDW(cA.z), wA3 = LDW(cA.w);

            for (; k + 12 <= d; k += 8) {
                int4 cB = *(const int4*)&slist[beg + k + 4];
                float2 vB0 = LDV(cB.x), vB1 = LDV(cB.y), vB2 = LDV(cB.z), vB3 = LDV(cB.w);
                unsigned wB0 = LDW(cB.x), wB1 = LDW(cB.y), wB2 = LDW(cB.z), wB3 = LDW(cB.w);
                COMP(vA0, wA0, ax0, ay0); COMP(vA1, wA1, ax1, ay1);
                COMP(vA2, wA2, ax2, ay2); COMP(vA3, wA3, ax3, ay3);
                int4 cN = *(const int4*)&slist[beg + k + 8];
                vA0 = LDV(cN.x); vA1 = LDV(cN.y); vA2 = LDV(cN.z); vA3 = LDV(cN.w);
                wA0 = LDW(cN.x); wA1 = LDW(cN.y); wA2 = LDW(cN.z); wA3 = LDW(cN.w);
                COMP(vB0, wB0, ax0, ay0); COMP(vB1, wB1, ax1, ay1);
                COMP(vB2, wB2, ax2, ay2); COMP(vB3, wB3, ax3, ay3);
            }
            if (k + 8 <= d) {
                int4 cB = *(const int4*)&slist[beg + k + 4];
                float2 vB0 = LDV(cB.x), vB1 = LDV(cB.y), vB2 = LDV(cB.z), vB3 = LDV(cB.w);
                unsigned wB0 = LDW(cB.x), wB1 = LDW(cB.y), wB2 = LDW(cB.z), wB3 = LDW(cB.w);
                COMP(vA0, wA0, ax0, ay0); COMP(vA1, wA1, ax1, ay1);
                COMP(vA2, wA2, ax2, ay2); COMP(vA3, wA3, ax3, ay3);
                COMP(vB0, wB0, ax0, ay0); COMP(vB1, wB1, ax1, ay1);
                COMP(vB2, wB2, ax2, ay2); COMP(vB3, wB3, ax3, ay3);
                k += 8;
            } else {
                COMP(vA0, wA0, ax0, ay0); COMP(vA1, wA1, ax1, ay1);
                COMP(vA2, wA2, ax2, ay2); COMP(vA3, wA3, ax3, ay3);
                k += 4;
            }
        }
        for (; k < d; ++k) {
            int c = slist[beg + k];
            float2 v = LDV(c);
            unsigned w = LDW(c);
            COMP(v, w, ax0, ay0);
        }
        float rx = (ax0 + ax1) + (ax2 + ax3);
        float ry = (ay0 + ay1) + (ay2 + ay3);
        rx = rx > 0.f ? rx : __expf(rx) - 1.f;
        ry = ry > 0.f ? ry : __expf(ry) - 1.f;
        ((float2*)out)[(unsigned)node * 64u + l] = make_float2(rx, ry);
    }
#undef LDV
#undef LDW
#undef COMP
}

extern "C" void kernel_launch(void* const* d_in, const int* in_sizes, int n_in,
                              void* d_out, int out_size, void* d_ws, size_t ws_size,
                              hipStream_t stream)
{
    const float* x  = (const float*)d_in[0];
    const float* W  = (const float*)d_in[1];
    const float* a  = (const float*)d_in[2];
    const int* esrc = (const int*)d_in[3];
    const int* edst = (const int*)d_in[4];
    const int n_nodes = in_sizes[0] / DIN;
    const int n_edges = in_sizes[3];
    float* out = (float*)d_out;

    const int nb = (n_nodes + BNODES - 1) >> BSH;

    // workspace layout (~46.7 MB)
    unsigned int* hq = (unsigned int*)d_ws;                 // [N*64] bf16 pairs, 25.6MB
    float2* usrc = (float2*)(hq + (size_t)n_nodes * 64);    // [N*4]
    float2* vdst = usrc + (size_t)n_nodes * NH;             // [N*4]
    int* gcur   = (int*)(vdst + (size_t)n_nodes * NH);      // [MAXB*GSTR], 64KB
    unsigned int* binned = (unsigned int*)(gcur + MAXB * GSTR); // [nb*BCAP], 17.6MB

    hipMemsetAsync(gcur, 0, MAXB * GSTR * sizeof(int), stream);

    const int nodeblks = (n_nodes + NPBF - 1) / NPBF;
    feat_kernel<<<nodeblks * 2, 256, 0, stream>>>(
        x, W, a, hq, usrc, vdst, n_nodes);

    binscatter_kernel<<<(n_edges + EPB - 1) / EPB, 256, 0, stream>>>(
        esrc, edst, gcur, binned, n_edges, nb);

    bucket_kernel<<<nb * 4, 512, 0, stream>>>(
        gcur, binned, hq, usrc, vdst, out, n_nodes);
}